// Round 9
// baseline (62.161 us; speedup 1.0000x reference)
//
#include <hip/hip_runtime.h>

typedef unsigned short u16;
typedef __attribute__((ext_vector_type(8))) short bf16x8;  // 8 bf16 = 4 VGPRs (MFMA A/B frag)
typedef __attribute__((ext_vector_type(4))) float f32x4;   // MFMA C/D frag

constexpr int   kN    = 8192;
constexpr int   kD    = 256;
constexpr float kInvD = 1.0f / 256.0f;
constexpr float kInv2D = 2.0f / 256.0f;   // 2/D
constexpr float kInvN = 1.0f / 8192.0f;

#define GLOAD_LDS16(gptr, ldsptr)                                                   \
  __builtin_amdgcn_global_load_lds(                                                 \
      (const __attribute__((address_space(1))) unsigned int*)(gptr),                \
      (__attribute__((address_space(3))) unsigned int*)(ldsptr), 16, 0, 0)

// ---------------------------------------------------------------------------
// Kernel 1: prep — f32 -> bf16 convert, packed {sum-of-squares, id} per row,
// zero out. One wave per row (4 rows / 256-thread block).
// ---------------------------------------------------------------------------
__global__ __launch_bounds__(256) void prep_kernel(
    const float* __restrict__ samples, const float* __restrict__ input1,
    u16* __restrict__ bf, float2* __restrict__ sqid, float* __restrict__ out)
{
  const int row  = blockIdx.x * 4 + (threadIdx.x >> 6);
  const int lane = threadIdx.x & 63;

  const float4 v = *(const float4*)(samples + (size_t)row * kD + lane * 4);

  float tmp[4] = {v.x, v.y, v.z, v.w};
  u16 h[4];
#pragma unroll
  for (int i = 0; i < 4; ++i) {
    union { float f; unsigned u; } c;
    c.f = tmp[i];
    unsigned r = c.u + 0x7fffu + ((c.u >> 16) & 1u);
    h[i] = (u16)(r >> 16);
  }
  *(ushort4*)(bf + (size_t)row * kD + lane * 4) = make_ushort4(h[0], h[1], h[2], h[3]);

  float ss = v.x * v.x + v.y * v.y + v.z * v.z + v.w * v.w;
#pragma unroll
  for (int m = 32; m >= 1; m >>= 1) ss += __shfl_xor(ss, m);

  if (lane == 0) {
    sqid[row] = make_float2(ss, input1[row * 32 + 7]);
    out[row]  = 0.0f;
  }
}

// ---------------------------------------------------------------------------
// Kernel 2: upper-triangle gram via R1's EXACT loop shape (the only config
// measured healthy: rolled contiguous-j tile loop, carried rowacc, 108 VGPR,
// 2.79 CU-us/tile).
//
// Grid (64 strips, 16 j-chunks of 4 tiles). Block (r,h): i0 = r*128,
// j0 = h*512 + jt*128 for jt=0..3 (contiguous, rolled, compile-time trip).
// Blocks with the whole chunk below the diagonal return immediately
// (480 empties retire in ~us). Boundary chunks compute below-diagonal tiles
// (4.4% MFMA waste) but mask their epilogue contribution multiplicatively —
// NO break/continue/runtime trip (R6/R7 spilled from those; R8's full
// unroll also degraded codegen to VGPR 80 / 2x slower K-steps).
//
// Per tile: BK=64 x 4 K-steps, 4 waves 2x2, mfma_f32_16x16x32_bf16 4x4/wave,
// global_load_lds 16B staging, XOR-swizzled source + swizzled ds_read_b128
// (rule #21, 0 conflicts measured R1-R8), setprio around MFMA.
// Epilogue: t = (S-1+eq)^2 * mask; rowacc carried across tiles (one row
// atomic set per block); col sums per tile when j0 > i0 (symmetry).
// ---------------------------------------------------------------------------
__global__ __launch_bounds__(256, 2) void simloss_main(
    const u16* __restrict__ bf, const float2* __restrict__ sqid,
    float* __restrict__ out)
{
  __shared__ u16 Abuf[128 * 64];  // 16 KB
  __shared__ u16 Bbuf[128 * 64];  // 16 KB

  const int i0    = blockIdx.x * 128;        // strip r = blockIdx.x (0..63)
  const int jbase = blockIdx.y * 512;        // chunk h = blockIdx.y (0..15)

  // whole chunk strictly below the diagonal -> nothing to do
  if (jbase + 512 <= i0) return;

  const int tid  = threadIdx.x;
  const int lane = tid & 63;
  const int w    = tid >> 6;       // wave 0..3
  const int wm   = w >> 1;         // wave row (0..1)
  const int wn   = w & 1;          // wave col (0..1)
  const int llo  = lane & 15;
  const int lhi  = lane >> 4;

  const int sr = tid >> 3;  // staging row within 32-row chunk
  const int sl = tid & 7;   // staging 16B slot within 128B row

  // i-side row data: block-constant, hoisted (R2-style, measured healthy)
  float sqi_s[4][4], idi[4][4];
#pragma unroll
  for (int mi = 0; mi < 4; ++mi)
#pragma unroll
    for (int rr = 0; rr < 4; ++rr) {
      const float2 p = sqid[i0 + wm * 64 + mi * 16 + lhi * 4 + rr];
      sqi_s[mi][rr] = p.x * kInvD;
      idi[mi][rr]   = p.y;
    }

  float rowacc[4][4] = {};  // carried across tiles (R1 pattern)

  for (int jt = 0; jt < 4; ++jt) {
    const int j0 = jbase + jt * 128;

    f32x4 acc[4][4];
#pragma unroll
    for (int mi = 0; mi < 4; ++mi)
#pragma unroll
      for (int ni = 0; ni < 4; ++ni) acc[mi][ni] = {0.f, 0.f, 0.f, 0.f};

#pragma unroll
    for (int kt = 0; kt < 4; ++kt) {
      const int k0 = kt * 64;
      // stage A[128x64] and B[128x64] bf16 tiles: 4 calls x 16B/thread each
#pragma unroll
      for (int cc = 0; cc < 4; ++cc) {
        const int rr  = cc * 32 + sr;
        const int ksl = sl ^ (rr & 7);  // inverse-swizzled global source
        const u16* ga = bf + (size_t)(i0 + rr) * kD + k0 + ksl * 8;
        const u16* gb = bf + (size_t)(j0 + rr) * kD + k0 + ksl * 8;
        GLOAD_LDS16(ga, Abuf + rr * 64 + sl * 8);  // linear dest = tid*16B
        GLOAD_LDS16(gb, Bbuf + rr * 64 + sl * 8);
      }
      __syncthreads();

#pragma unroll
      for (int k32 = 0; k32 < 2; ++k32) {
        bf16x8 a[4], bv[4];
#pragma unroll
        for (int mi = 0; mi < 4; ++mi) {
          const int ra   = wm * 64 + mi * 16 + llo;
          const int slot = (k32 * 4 + lhi) ^ (ra & 7);  // swizzled read
          a[mi] = *(const bf16x8*)(Abuf + ra * 64 + slot * 8);
        }
#pragma unroll
        for (int ni = 0; ni < 4; ++ni) {
          const int rb   = wn * 64 + ni * 16 + llo;
          const int slot = (k32 * 4 + lhi) ^ (rb & 7);
          bv[ni] = *(const bf16x8*)(Bbuf + rb * 64 + slot * 8);
        }
        __builtin_amdgcn_s_setprio(1);
#pragma unroll
        for (int mi = 0; mi < 4; ++mi)
#pragma unroll
          for (int ni = 0; ni < 4; ++ni)
            acc[mi][ni] = __builtin_amdgcn_mfma_f32_16x16x32_bf16(
                a[mi], bv[ni], acc[mi][ni], 0, 0, 0);
        __builtin_amdgcn_s_setprio(0);
      }
      __syncthreads();
    }

    // ---- per-tile epilogue ----
    // mask: 1.0 for tiles on/above the diagonal, 0.0 below (no control flow)
    const float wmask = (j0 >= i0) ? 1.0f : 0.0f;

    float sqjm1[4], idj[4];
#pragma unroll
    for (int ni = 0; ni < 4; ++ni) {
      const float2 p = sqid[j0 + wn * 64 + ni * 16 + llo];
      sqjm1[ni] = p.x * kInvD - 1.0f;
      idj[ni]   = p.y;
    }

    float colacc[4] = {};
#pragma unroll
    for (int mi = 0; mi < 4; ++mi)
#pragma unroll
      for (int ni = 0; ni < 4; ++ni)
#pragma unroll
        for (int rr = 0; rr < 4; ++rr) {
          // S-1 = (sq_i + sq_j)/D - 1 - (2/D)*gram ; +1 if same id
          float s1 = fmaf(acc[mi][ni][rr], -kInv2D, sqi_s[mi][rr] + sqjm1[ni]);
          s1 += (idi[mi][rr] == idj[ni]) ? 1.0f : 0.0f;
          const float tt = s1 * s1 * wmask;
          rowacc[mi][rr] += tt;
          colacc[ni] += tt;
        }

    // col sums per tile, only strictly above the diagonal (symmetry partner)
    if (j0 > i0) {
#pragma unroll
      for (int ni = 0; ni < 4; ++ni) {
        float v = colacc[ni];
        v += __shfl_xor(v, 16);
        v += __shfl_xor(v, 32);
        if (lhi == 0)
          atomicAdd(&out[j0 + wn * 64 + ni * 16 + llo], v * kInvN);
      }
    }
  }

  // ---- block end: row sums (carried across tiles, R1 pattern) ----
#pragma unroll
  for (int mi = 0; mi < 4; ++mi)
#pragma unroll
    for (int rr = 0; rr < 4; ++rr) {
      float v = rowacc[mi][rr];
      v += __shfl_xor(v, 1);
      v += __shfl_xor(v, 2);
      v += __shfl_xor(v, 4);
      v += __shfl_xor(v, 8);
      if (llo == 0)
        atomicAdd(&out[i0 + wm * 64 + mi * 16 + lhi * 4 + rr], v * kInvN);
    }
}

// ---------------------------------------------------------------------------
extern "C" void kernel_launch(void* const* d_in, const int* in_sizes, int n_in,
                              void* d_out, int out_size, void* d_ws, size_t ws_size,
                              hipStream_t stream) {
  const float* samples = (const float*)d_in[0];
  const float* input1  = (const float*)d_in[1];
  float* out = (float*)d_out;

  char* ws = (char*)d_ws;
  u16*    bf   = (u16*)ws;                                  // 4 MB bf16 samples
  float2* sqid = (float2*)(ws + (size_t)4 * 1024 * 1024);   // 64 KB {sq, id}

  prep_kernel<<<kN / 4, 256, 0, stream>>>(samples, input1, bf, sqid, out);
  simloss_main<<<dim3(64, 16), 256, 0, stream>>>(bf, sqid, out);
}

// Round 10
// 46.078 us; speedup vs baseline: 1.3491x; 1.3491x over previous
//
#include <hip/hip_runtime.h>

typedef unsigned short u16;
typedef __attribute__((ext_vector_type(8))) short bf16x8;  // 8 bf16 = 4 VGPRs (MFMA A/B frag)
typedef __attribute__((ext_vector_type(4))) float f32x4;   // MFMA C/D frag

constexpr int   kN    = 8192;
constexpr int   kD    = 256;
constexpr float kInvD = 1.0f / 256.0f;
constexpr float kInv2D = 2.0f / 256.0f;   // 2/D
constexpr float kInvN = 1.0f / 8192.0f;

#define GLOAD_LDS16(gptr, ldsptr)                                                   \
  __builtin_amdgcn_global_load_lds(                                                 \
      (const __attribute__((address_space(1))) unsigned int*)(gptr),                \
      (__attribute__((address_space(3))) unsigned int*)(ldsptr), 16, 0, 0)

// ---------------------------------------------------------------------------
// Kernel 1: prep — f32 -> bf16 convert, packed {sum-of-squares, id} per row,
// zero out. One wave per row (4 rows / 256-thread block).
// ---------------------------------------------------------------------------
__global__ __launch_bounds__(256) void prep_kernel(
    const float* __restrict__ samples, const float* __restrict__ input1,
    u16* __restrict__ bf, float2* __restrict__ sqid, float* __restrict__ out)
{
  const int row  = blockIdx.x * 4 + (threadIdx.x >> 6);
  const int lane = threadIdx.x & 63;

  const float4 v = *(const float4*)(samples + (size_t)row * kD + lane * 4);

  float tmp[4] = {v.x, v.y, v.z, v.w};
  u16 h[4];
#pragma unroll
  for (int i = 0; i < 4; ++i) {
    union { float f; unsigned u; } c;
    c.f = tmp[i];
    unsigned r = c.u + 0x7fffu + ((c.u >> 16) & 1u);
    h[i] = (u16)(r >> 16);
  }
  *(ushort4*)(bf + (size_t)row * kD + lane * 4) = make_ushort4(h[0], h[1], h[2], h[3]);

  float ss = v.x * v.x + v.y * v.y + v.z * v.z + v.w * v.w;
#pragma unroll
  for (int m = 32; m >= 1; m >>= 1) ss += __shfl_xor(ss, m);

  if (lane == 0) {
    sqid[row] = make_float2(ss, input1[row * 32 + 7]);
    out[row]  = 0.0f;
  }
}

// ---------------------------------------------------------------------------
// Kernel 2: triangle via wrapped offsets, EXACTLY 512 live blocks.
//
// Grid quantization was R9's cost (544 live blocks / 512 co-residency slots
// = 2.125 rounds; per-tile parity with R1 was already there). Here: strip
// r = blockIdx.x covers tile-distances c = 4*blockIdx.y + t, t=0..3 (rolled
// loop, R9's exact healthy shape: hoisted i-side, carried rowacc, LB(256,2),
// VGPR 120, no spill). 64 x 8 = 512 blocks = 256 CU x 2 -> ONE round.
//
// Coverage (no mask, no dead blocks, no double count): pair {a,b}, a<b,
// d = b-a: covered by strip a iff d <= 31; by strip b iff 64-d <= 31
// (i.e. d >= 33); d = 0 is the diagonal tile, computed fully, row-sums only.
// d = 32 covered by NEITHER -> separate 32-block kernel below.
//
// Per tile: BK=64 x 4 K-steps, 4 waves 2x2, mfma_f32_16x16x32_bf16 4x4/wave,
// global_load_lds 16B staging, XOR-swizzled source + swizzled ds_read_b128
// (rule #21, 0 conflicts measured R1-R9), setprio around MFMA. Epilogue
// folds (S-1+eq)^2; rowacc carried across tiles (one row-atomic set per
// block); per-tile col atomics for c != 0 (symmetry partner).
// ---------------------------------------------------------------------------
__global__ __launch_bounds__(256, 2) void simloss_main(
    const u16* __restrict__ bf, const float2* __restrict__ sqid,
    float* __restrict__ out)
{
  __shared__ u16 Abuf[128 * 64];  // 16 KB
  __shared__ u16 Bbuf[128 * 64];  // 16 KB

  const int tid  = threadIdx.x;
  const int lane = tid & 63;
  const int w    = tid >> 6;       // wave 0..3
  const int wm   = w >> 1;         // wave row (0..1)
  const int wn   = w & 1;          // wave col (0..1)
  const int llo  = lane & 15;
  const int lhi  = lane >> 4;

  const int r  = blockIdx.x;       // strip 0..63
  const int h  = blockIdx.y;       // offset chunk 0..7
  const int i0 = r * 128;

  const int sr = tid >> 3;  // staging row within 32-row chunk
  const int sl = tid & 7;   // staging 16B slot within 128B row

  // i-side row data: block-constant, hoisted (R9-measured healthy)
  float sqi_s[4][4], idi[4][4];
#pragma unroll
  for (int mi = 0; mi < 4; ++mi)
#pragma unroll
    for (int rr = 0; rr < 4; ++rr) {
      const float2 p = sqid[i0 + wm * 64 + mi * 16 + lhi * 4 + rr];
      sqi_s[mi][rr] = p.x * kInvD;
      idi[mi][rr]   = p.y;
    }

  float rowacc[4][4] = {};  // carried across tiles

  for (int t = 0; t < 4; ++t) {
    const int c  = h * 4 + t;            // tile distance 0..31
    const int j0 = ((r + c) & 63) * 128;

    f32x4 acc[4][4];
#pragma unroll
    for (int mi = 0; mi < 4; ++mi)
#pragma unroll
      for (int ni = 0; ni < 4; ++ni) acc[mi][ni] = {0.f, 0.f, 0.f, 0.f};

#pragma unroll
    for (int kt = 0; kt < 4; ++kt) {
      const int k0 = kt * 64;
      // stage A[128x64] and B[128x64] bf16 tiles: 4 calls x 16B/thread each
#pragma unroll
      for (int cc = 0; cc < 4; ++cc) {
        const int rr  = cc * 32 + sr;
        const int ksl = sl ^ (rr & 7);  // inverse-swizzled global source
        const u16* ga = bf + (size_t)(i0 + rr) * kD + k0 + ksl * 8;
        const u16* gb = bf + (size_t)(j0 + rr) * kD + k0 + ksl * 8;
        GLOAD_LDS16(ga, Abuf + rr * 64 + sl * 8);  // linear dest = tid*16B
        GLOAD_LDS16(gb, Bbuf + rr * 64 + sl * 8);
      }
      __syncthreads();

#pragma unroll
      for (int k32 = 0; k32 < 2; ++k32) {
        bf16x8 a[4], bv[4];
#pragma unroll
        for (int mi = 0; mi < 4; ++mi) {
          const int ra   = wm * 64 + mi * 16 + llo;
          const int slot = (k32 * 4 + lhi) ^ (ra & 7);  // swizzled read
          a[mi] = *(const bf16x8*)(Abuf + ra * 64 + slot * 8);
        }
#pragma unroll
        for (int ni = 0; ni < 4; ++ni) {
          const int rb   = wn * 64 + ni * 16 + llo;
          const int slot = (k32 * 4 + lhi) ^ (rb & 7);
          bv[ni] = *(const bf16x8*)(Bbuf + rb * 64 + slot * 8);
        }
        __builtin_amdgcn_s_setprio(1);
#pragma unroll
        for (int mi = 0; mi < 4; ++mi)
#pragma unroll
          for (int ni = 0; ni < 4; ++ni)
            acc[mi][ni] = __builtin_amdgcn_mfma_f32_16x16x32_bf16(
                a[mi], bv[ni], acc[mi][ni], 0, 0, 0);
        __builtin_amdgcn_s_setprio(0);
      }
      __syncthreads();
    }

    // ---- per-tile epilogue ----
    float sqjm1[4], idj[4];
#pragma unroll
    for (int ni = 0; ni < 4; ++ni) {
      const float2 p = sqid[j0 + wn * 64 + ni * 16 + llo];
      sqjm1[ni] = p.x * kInvD - 1.0f;
      idj[ni]   = p.y;
    }

    float colacc[4] = {};
#pragma unroll
    for (int mi = 0; mi < 4; ++mi)
#pragma unroll
      for (int ni = 0; ni < 4; ++ni)
#pragma unroll
        for (int rr = 0; rr < 4; ++rr) {
          // S-1 = (sq_i + sq_j)/D - 1 - (2/D)*gram ; +1 if same id
          float s1 = fmaf(acc[mi][ni][rr], -kInv2D, sqi_s[mi][rr] + sqjm1[ni]);
          s1 += (idi[mi][rr] == idj[ni]) ? 1.0f : 0.0f;
          const float tt = s1 * s1;
          rowacc[mi][rr] += tt;
          colacc[ni] += tt;
        }

    // col sums per tile (symmetry partner) — diagonal tile (c==0) excluded
    if (c != 0) {
#pragma unroll
      for (int ni = 0; ni < 4; ++ni) {
        float v = colacc[ni];
        v += __shfl_xor(v, 16);
        v += __shfl_xor(v, 32);
        if (lhi == 0)
          atomicAdd(&out[j0 + wn * 64 + ni * 16 + llo], v * kInvN);
      }
    }
  }

  // ---- block end: row sums (carried across tiles) ----
#pragma unroll
  for (int mi = 0; mi < 4; ++mi)
#pragma unroll
    for (int rr = 0; rr < 4; ++rr) {
      float v = rowacc[mi][rr];
      v += __shfl_xor(v, 1);
      v += __shfl_xor(v, 2);
      v += __shfl_xor(v, 4);
      v += __shfl_xor(v, 8);
      if (llo == 0)
        atomicAdd(&out[i0 + wm * 64 + mi * 16 + lhi * 4 + rr], v * kInvN);
    }
}

// ---------------------------------------------------------------------------
// Kernel 3: the 32 distance-32 tiles (pairs {a, a+32}) — not covered by the
// wrapped offsets above. 32 single-tile blocks, R4's proven body, runs in
// ~5 us solo. Kept separate so the main kernel's codegen stays untouched.
// ---------------------------------------------------------------------------
__global__ __launch_bounds__(256, 2) void simloss_d32(
    const u16* __restrict__ bf, const float2* __restrict__ sqid,
    float* __restrict__ out)
{
  __shared__ u16 Abuf[128 * 64];
  __shared__ u16 Bbuf[128 * 64];

  const int tid  = threadIdx.x;
  const int lane = tid & 63;
  const int w    = tid >> 6;
  const int wm   = w >> 1;
  const int wn   = w & 1;
  const int llo  = lane & 15;
  const int lhi  = lane >> 4;

  const int i0 = blockIdx.x * 128;          // strips 0..31
  const int j0 = (blockIdx.x + 32) * 128;   // partner strip

  const int sr = tid >> 3;
  const int sl = tid & 7;

  f32x4 acc[4][4];
#pragma unroll
  for (int mi = 0; mi < 4; ++mi)
#pragma unroll
    for (int ni = 0; ni < 4; ++ni) acc[mi][ni] = {0.f, 0.f, 0.f, 0.f};

#pragma unroll
  for (int kt = 0; kt < 4; ++kt) {
    const int k0 = kt * 64;
#pragma unroll
    for (int cc = 0; cc < 4; ++cc) {
      const int rr  = cc * 32 + sr;
      const int ksl = sl ^ (rr & 7);
      const u16* ga = bf + (size_t)(i0 + rr) * kD + k0 + ksl * 8;
      const u16* gb = bf + (size_t)(j0 + rr) * kD + k0 + ksl * 8;
      GLOAD_LDS16(ga, Abuf + rr * 64 + sl * 8);
      GLOAD_LDS16(gb, Bbuf + rr * 64 + sl * 8);
    }
    __syncthreads();

#pragma unroll
    for (int k32 = 0; k32 < 2; ++k32) {
      bf16x8 a[4], bv[4];
#pragma unroll
      for (int mi = 0; mi < 4; ++mi) {
        const int ra   = wm * 64 + mi * 16 + llo;
        const int slot = (k32 * 4 + lhi) ^ (ra & 7);
        a[mi] = *(const bf16x8*)(Abuf + ra * 64 + slot * 8);
      }
#pragma unroll
      for (int ni = 0; ni < 4; ++ni) {
        const int rb   = wn * 64 + ni * 16 + llo;
        const int slot = (k32 * 4 + lhi) ^ (rb & 7);
        bv[ni] = *(const bf16x8*)(Bbuf + rb * 64 + slot * 8);
      }
      __builtin_amdgcn_s_setprio(1);
#pragma unroll
      for (int mi = 0; mi < 4; ++mi)
#pragma unroll
        for (int ni = 0; ni < 4; ++ni)
          acc[mi][ni] = __builtin_amdgcn_mfma_f32_16x16x32_bf16(
              a[mi], bv[ni], acc[mi][ni], 0, 0, 0);
      __builtin_amdgcn_s_setprio(0);
    }
    __syncthreads();
  }

  float sqi_s[4][4], idi[4][4];
#pragma unroll
  for (int mi = 0; mi < 4; ++mi)
#pragma unroll
    for (int rr = 0; rr < 4; ++rr) {
      const float2 p = sqid[i0 + wm * 64 + mi * 16 + lhi * 4 + rr];
      sqi_s[mi][rr] = p.x * kInvD;
      idi[mi][rr]   = p.y;
    }
  float sqjm1[4], idj[4];
#pragma unroll
  for (int ni = 0; ni < 4; ++ni) {
    const float2 p = sqid[j0 + wn * 64 + ni * 16 + llo];
    sqjm1[ni] = p.x * kInvD - 1.0f;
    idj[ni]   = p.y;
  }

  float rowacc[4][4] = {};
  float colacc[4] = {};
#pragma unroll
  for (int mi = 0; mi < 4; ++mi)
#pragma unroll
    for (int ni = 0; ni < 4; ++ni)
#pragma unroll
      for (int rr = 0; rr < 4; ++rr) {
        float s1 = fmaf(acc[mi][ni][rr], -kInv2D, sqi_s[mi][rr] + sqjm1[ni]);
        s1 += (idi[mi][rr] == idj[ni]) ? 1.0f : 0.0f;
        const float tt = s1 * s1;
        rowacc[mi][rr] += tt;
        colacc[ni] += tt;
      }

#pragma unroll
  for (int mi = 0; mi < 4; ++mi)
#pragma unroll
    for (int rr = 0; rr < 4; ++rr) {
      float v = rowacc[mi][rr];
      v += __shfl_xor(v, 1);
      v += __shfl_xor(v, 2);
      v += __shfl_xor(v, 4);
      v += __shfl_xor(v, 8);
      if (llo == 0)
        atomicAdd(&out[i0 + wm * 64 + mi * 16 + lhi * 4 + rr], v * kInvN);
    }
#pragma unroll
  for (int ni = 0; ni < 4; ++ni) {
    float v = colacc[ni];
    v += __shfl_xor(v, 16);
    v += __shfl_xor(v, 32);
    if (lhi == 0)
      atomicAdd(&out[j0 + wn * 64 + ni * 16 + llo], v * kInvN);
  }
}

// ---------------------------------------------------------------------------
extern "C" void kernel_launch(void* const* d_in, const int* in_sizes, int n_in,
                              void* d_out, int out_size, void* d_ws, size_t ws_size,
                              hipStream_t stream) {
  const float* samples = (const float*)d_in[0];
  const float* input1  = (const float*)d_in[1];
  float* out = (float*)d_out;

  char* ws = (char*)d_ws;
  u16*    bf   = (u16*)ws;                                  // 4 MB bf16 samples
  float2* sqid = (float2*)(ws + (size_t)4 * 1024 * 1024);   // 64 KB {sq, id}

  prep_kernel<<<kN / 4, 256, 0, stream>>>(samples, input1, bf, sqid, out);
  simloss_main<<<dim3(64, 8), 256, 0, stream>>>(bf, sqid, out);
  simloss_d32<<<32, 256, 0, stream>>>(bf, sqid, out);
}